// Round 12
// baseline (132.103 us; speedup 1.0000x reference)
//
#include <hip/hip_runtime.h>
#include <hip/hip_bf16.h>
#include <stdint.h>

// Problem constants
#define E_  1024
#define H_  16
#define D_  64
#define T_  2048
#define B_  2

typedef unsigned short u16;
typedef unsigned char u8;
typedef __attribute__((ext_vector_type(8))) __bf16 bf16x8;
typedef __attribute__((ext_vector_type(4))) float f32x4;
typedef __attribute__((ext_vector_type(8))) u16 u16x8;
typedef __attribute__((ext_vector_type(4))) u16 u16x4;

__device__ __forceinline__ float bf2f(u16 u) {
  union { uint32_t u32; float f; } x; x.u32 = ((uint32_t)u) << 16; return x.f;
}
__device__ __forceinline__ u16 f2bf(float v) {
  union { float f; uint32_t u; } x; x.f = v;
  uint32_t r = x.u + 0x7fffu + ((x.u >> 16) & 1u);  // round-to-nearest-even
  return (u16)(r >> 16);
}
__device__ __forceinline__ void async16(const void* g, void* l) {
  __builtin_amdgcn_global_load_lds(
      (const __attribute__((address_space(1))) void*)g,
      (__attribute__((address_space(3))) void*)l, 16, 0, 0);
}
// key permutation within a 64-key tile: LDS/MFMA k-order j for actual key k.
// j = {K5, K3, K2, K4, K1, K0}  (so producer P registers == PV A-fragment)
__device__ __forceinline__ int jperm(int k) {
  return (k & 35) | ((k & 12) << 1) | ((k & 16) >> 2);
}

// Per-kernel dtype self-detection (wave-uniform): sample even u16 halves of
// the tensor's first 256B. bf16 -> exponents ~[118,130]; f32 low-halves are
// mantissa bits -> ~37-50% extreme. All-zero -> bf16 path (harmless).
__device__ __forceinline__ int detect_f32(const void* src) {
  u16 u = ((const u16*)src)[2 * (threadIdx.x & 63)];
  int e = (u >> 7) & 0xFF;
  int ex = (e != 0 && (e <= 0x40 || e >= 0xC0)) ? 1 : 0;
  return __popcll(__ballot(ex)) > 16;
}

// canonicalize x to bf16
__global__ __launch_bounds__(256) void convf_kernel(const void* __restrict__ src,
                                                    u16* __restrict__ dst, int n) {
  const int f32in = detect_f32(src);
  int i = (blockIdx.x * 256 + threadIdx.x) * 8;
  if (i >= n) return;
  if (f32in) {
    const float* s = (const float*)src;
    u16x8 o;
#pragma unroll
    for (int j = 0; j < 8; ++j) o[j] = f2bf(s[i + j]);
    *(u16x8*)(dst + i) = o;
  } else {
    *(u16x8*)(dst + i) = *(const u16x8*)((const u16*)src + i);
  }
}

// all four biases in one dispatch; dst slots spaced 2048 elems apart
__global__ __launch_bounds__(256) void bias4_kernel(
    const void* __restrict__ b0, const void* __restrict__ b1,
    const void* __restrict__ b2, const void* __restrict__ b3,
    u16* __restrict__ dst) {
  const void* src = (blockIdx.x == 0) ? b0 : (blockIdx.x == 1) ? b1
                    : (blockIdx.x == 2) ? b2 : b3;
  const int f32in = detect_f32(src);
  u16* d = dst + blockIdx.x * 2048;
  int t = threadIdx.x;
#pragma unroll
  for (int j = 0; j < 4; ++j) {
    int i = t + j * 256;
    d[i] = f32in ? f2bf(((const float*)src)[i]) : ((const u16*)src)[i];
  }
}

// mask -> log2-domain additive constant in BF16: keep -> -SH, drop -> -30000
// (keep value rounds uniformly; a uniform shift cancels in softmax normalize)
__global__ __launch_bounds__(256) void maskbias_kernel(const void* __restrict__ mp,
                                                       u16* __restrict__ mbh) {
  unsigned w0 = ((const unsigned*)mp)[threadIdx.x & 63];
  int isInt = (__ballot(w0 > 1u) == 0ull);  // int32 bools are 0/1 only
  int i = blockIdx.x * 256 + threadIdx.x;   // 4096 total
  int keep = isInt ? (((const int*)mp)[i] != 0) : (((const u8*)mp)[i] != 0);
  mbh[i] = keep ? f2bf(-5.77078016f) : f2bf(-30000.f);
}

// fused weight convert + transpose, all 4 weights in one dispatch (z selects)
__global__ __launch_bounds__(256) void wtc4_kernel(
    const void* __restrict__ W0, const void* __restrict__ W1,
    const void* __restrict__ W2, const void* __restrict__ W3,
    u16* __restrict__ T0, u16* __restrict__ T1,
    u16* __restrict__ T2, u16* __restrict__ T3) {
  __shared__ __align__(16) u16 tile[64][65];
  const int z = blockIdx.z;
  const void* Wv = (z == 0) ? W0 : (z == 1) ? W1 : (z == 2) ? W2 : W3;
  u16* WT = (z == 0) ? T0 : (z == 1) ? T1 : (z == 2) ? T2 : T3;
  const int f32in = detect_f32(Wv);
  const int bx = blockIdx.x * 64, by = blockIdx.y * 64;
  const int t = threadIdx.x;
#pragma unroll
  for (int p = 0; p < 2; ++p) {
    int row = p * 32 + (t >> 3);
    int ch = t & 7;
    if (f32in) {
      const float* s = (const float*)Wv + (size_t)(by + row) * E_ + bx + ch * 8;
#pragma unroll
      for (int j = 0; j < 8; ++j) tile[row][ch * 8 + j] = f2bf(s[j]);
    } else {
      u16x8 v = *(const u16x8*)((const u16*)Wv + (size_t)(by + row) * E_ + bx + ch * 8);
#pragma unroll
      for (int j = 0; j < 8; ++j) tile[row][ch * 8 + j] = v[j];
    }
  }
  __syncthreads();
#pragma unroll
  for (int p = 0; p < 2; ++p) {
    int orow = p * 32 + (t >> 3);
    int ch = t & 7;
    u16x8 v;
#pragma unroll
    for (int j = 0; j < 8; ++j) v[j] = tile[ch * 8 + j][orow];
    *(u16x8*)(WT + (size_t)(bx + orow) * E_ + by + ch * 8) = v;
  }
}

// ---------------- fused QKV GEMM -------------------------------------------
// V^T is stored with jperm-permuted t-order within each 64-key block so the
// attention PV B-operand matches the in-register P fragments.
__global__ __launch_bounds__(256, 2) void gemm_qkv_kernel(
    const u16* __restrict__ A, const u16* __restrict__ BTm,
    const u16* __restrict__ biases, u16* __restrict__ Qb,
    u16* __restrict__ Kb, u16* __restrict__ Vtb) {
  __shared__ __align__(16) u16 As[128 * 64];
  __shared__ __align__(16) u16 Bs[128 * 64];
  const int tid = threadIdx.x, lane = tid & 63, wid = tid >> 6;
  const int wm = wid >> 1, wn = wid & 1;
  const int l15 = lane & 15, lg = lane >> 4;
  const int r0 = blockIdx.x * 128, c0 = blockIdx.y * 128;
  f32x4 acc[4][4] = {};

  for (int k0 = 0; k0 < E_; k0 += 64) {
    __syncthreads();
#pragma unroll
    for (int i = 0; i < 4; ++i) {
      int row = i * 32 + (tid >> 3);
      int g = (tid & 7) ^ (row & 7);
      async16(A + (size_t)(r0 + row) * E_ + k0 + g * 8,
              (char*)As + i * 4096 + tid * 16);
      async16(BTm + (size_t)(c0 + row) * E_ + k0 + g * 8,
              (char*)Bs + i * 4096 + tid * 16);
    }
    __syncthreads();
#pragma unroll
    for (int kk = 0; kk < 2; ++kk) {
      bf16x8 af[4], bfr[4];
#pragma unroll
      for (int mt = 0; mt < 4; ++mt) {
        int rowa = wm * 64 + mt * 16 + l15;
        int sa = (kk * 4 + lg) ^ (rowa & 7);
        af[mt] = *(const bf16x8*)((const char*)As + rowa * 128 + sa * 16);
        int rowb = wn * 64 + mt * 16 + l15;
        int sb = (kk * 4 + lg) ^ (rowb & 7);
        bfr[mt] = *(const bf16x8*)((const char*)Bs + rowb * 128 + sb * 16);
      }
#pragma unroll
      for (int mt = 0; mt < 4; ++mt)
#pragma unroll
        for (int nt = 0; nt < 4; ++nt)
          acc[mt][nt] = __builtin_amdgcn_mfma_f32_16x16x32_bf16(
              af[mt], bfr[nt], acc[mt][nt], 0, 0, 0);
    }
  }

  const int sel = c0 >> 10;           // 0=Q, 1=K, 2=V
  u16* outp = (sel == 0) ? Qb : Kb;
#pragma unroll
  for (int mt = 0; mt < 4; ++mt) {
#pragma unroll
    for (int nt = 0; nt < 4; ++nt) {
      int colG = c0 + wn * 64 + nt * 16 + l15;
      int colL = colG & 1023;
      float bv = bf2f(biases[sel * 2048 + colL]);
      int rbase = r0 + wm * 64 + mt * 16 + lg * 4;
      int hh = colL >> 6, dd = colL & 63;
      if (sel == 2) {  // V^T (B,H,D,T) with jperm'd t within 64-blocks
        int bb = rbase >> 11, t0 = rbase & (T_ - 1);
        int tp = (t0 & ~63) | jperm(t0 & 63);   // low 2 bits preserved
        u16x4 pk;
#pragma unroll
        for (int r = 0; r < 4; ++r) pk[r] = f2bf(acc[mt][nt][r] + bv);
        *(u16x4*)(Vtb + (size_t)((bb * H_ + hh) * D_ + dd) * T_ + tp) = pk;
      } else {         // Q/K (B,H,T,D)
#pragma unroll
        for (int r = 0; r < 4; ++r) {
          int row = rbase + r;
          int bb = row >> 11, t = row & (T_ - 1);
          outp[(size_t)((bb * H_ + hh) * T_ + t) * D_ + dd] =
              f2bf(acc[mt][nt][r] + bv);
        }
      }
    }
  }
}

// ---------------- final GEMM: f32 output -----------------------------------
__global__ __launch_bounds__(256, 2) void gemm_out_kernel(
    const u16* __restrict__ A, const u16* __restrict__ BTm,
    const u16* __restrict__ bias, float* __restrict__ out) {
  __shared__ __align__(16) u16 As[128 * 64];
  __shared__ __align__(16) u16 Bs[128 * 64];
  const int tid = threadIdx.x, lane = tid & 63, wid = tid >> 6;
  const int wm = wid >> 1, wn = wid & 1;
  const int l15 = lane & 15, lg = lane >> 4;
  const int r0 = blockIdx.x * 128, c0 = blockIdx.y * 128;
  f32x4 acc[4][4] = {};

  for (int k0 = 0; k0 < E_; k0 += 64) {
    __syncthreads();
#pragma unroll
    for (int i = 0; i < 4; ++i) {
      int row = i * 32 + (tid >> 3);
      int g = (tid & 7) ^ (row & 7);
      async16(A + (size_t)(r0 + row) * E_ + k0 + g * 8,
              (char*)As + i * 4096 + tid * 16);
      async16(BTm + (size_t)(c0 + row) * E_ + k0 + g * 8,
              (char*)Bs + i * 4096 + tid * 16);
    }
    __syncthreads();
#pragma unroll
    for (int kk = 0; kk < 2; ++kk) {
      bf16x8 af[4], bfr[4];
#pragma unroll
      for (int mt = 0; mt < 4; ++mt) {
        int rowa = wm * 64 + mt * 16 + l15;
        int sa = (kk * 4 + lg) ^ (rowa & 7);
        af[mt] = *(const bf16x8*)((const char*)As + rowa * 128 + sa * 16);
        int rowb = wn * 64 + mt * 16 + l15;
        int sb = (kk * 4 + lg) ^ (rowb & 7);
        bfr[mt] = *(const bf16x8*)((const char*)Bs + rowb * 128 + sb * 16);
      }
#pragma unroll
      for (int mt = 0; mt < 4; ++mt)
#pragma unroll
        for (int nt = 0; nt < 4; ++nt)
          acc[mt][nt] = __builtin_amdgcn_mfma_f32_16x16x32_bf16(
              af[mt], bfr[nt], acc[mt][nt], 0, 0, 0);
    }
  }

#pragma unroll
  for (int mt = 0; mt < 4; ++mt)
#pragma unroll
    for (int nt = 0; nt < 4; ++nt) {
      int col = c0 + wn * 64 + nt * 16 + l15;
      float bv = bf2f(bias[col]);
      int rbase = r0 + wm * 64 + mt * 16 + lg * 4;
#pragma unroll
      for (int r = 0; r < 4; ++r)
        out[(size_t)(rbase + r) * E_ + col] = acc[mt][nt][r] + bv;
    }
}

// ---------------- MFMA flash attention (q-tile 64, 4 blocks/CU) -------------
// P fully in registers (swapped QK^T + jperm'd V). 4 waves x 16 q-rows each;
// grid 1024 -> 4 blocks/CU -> 4 waves/SIMD (the round-11 limiter was 2).
// LDS 36KB: 2-buf K/V dbuf (32KB) + bf16 mask bias (4KB); epilogue scratch
// aliases the dead K buffer after the final barrier.
__global__ __launch_bounds__(256, 4) void attn_kernel(
    const u16* __restrict__ Q, const u16* __restrict__ K,
    const u16* __restrict__ VT, const u16* __restrict__ mbg,
    u16* __restrict__ outb) {
  __shared__ __align__(16) u16 Ks[2][64 * 64];      // [buf][key][d] swizzled
  __shared__ __align__(16) u16 Vs[2][64 * 64];      // [buf][d][key-perm] swz
  __shared__ __align__(16) u16 mbh[T_];             // bf16 log2-domain bias
  // XCD-local decode: all 32 q-blocks of a head land on one XCD (L2 reuse)
  const int wg = blockIdx.x;
  const int xcd = wg & 7, slot = wg >> 3;           // slot 0..127
  const int bh = xcd + 8 * (slot >> 5);
  const int q0 = (slot & 31) * 64;
  const int b = bh >> 4, h = bh & 15;
  const int tid = threadIdx.x, lane = tid & 63, w = tid >> 6;
  const int l15 = lane & 15, lg = lane >> 4;

  const u16* qb = Q + (size_t)bh * T_ * D_;
  const u16* kb = K + (size_t)bh * T_ * D_;
  const u16* vb = VT + (size_t)bh * D_ * T_;

  // mask bias -> LDS (once, bf16)
  *(u16x8*)&mbh[tid * 8] = *(const u16x8*)(mbg + b * T_ + tid * 8);

  bf16x8 qf[2];  // Q hoisted: B-frag col=l15(q), k=kd*32+lg*8
#pragma unroll
  for (int kd = 0; kd < 2; ++kd) {
    int row = q0 + w * 16 + l15;
    qf[kd] = *(const bf16x8*)(qb + (size_t)row * D_ + kd * 32 + lg * 8);
  }

#define STAGE(kt_, bi_)                                                  \
  do {                                                                   \
    _Pragma("unroll")                                                    \
    for (int c = 0; c < 2; ++c) {                                        \
      int row_ = c * 32 + (tid >> 3);                                    \
      int g_ = (tid & 7) ^ (row_ & 7);                                   \
      async16(kb + (size_t)((kt_) * 64 + row_) * D_ + g_ * 8,            \
              (char*)&Ks[bi_][0] + c * 4096 + tid * 16);                 \
      async16(vb + (size_t)row_ * T_ + (kt_) * 64 + g_ * 8,              \
              (char*)&Vs[bi_][0] + c * 4096 + tid * 16);                 \
    }                                                                    \
  } while (0)

  STAGE(0, 0);
  __syncthreads();   // drains vmcnt(0): tile 0 + mbh ready

  f32x4 o[4] = {};
  float lrow = 0.f;
  const float cc = 0.125f * 1.44269504f;  // scale * log2(e)

  for (int kt = 0; kt < 32; ++kt) {
    const int cur = kt & 1;
    if (kt < 31) STAGE(kt + 1, cur ^ 1);  // prefetch, no wait
    const char* Kc = (const char*)&Ks[cur][0];
    const char* Vc = (const char*)&Vs[cur][0];

    // mask bias for this tile (LDS b64 broadcast; hidden under QK^T)
    u16x4 mraw[4];
#pragma unroll
    for (int mf = 0; mf < 4; ++mf)
      mraw[mf] = *(const u16x4*)&mbh[kt * 64 + mf * 16 + lg * 4];

    // S^T = K Q^T  (C: col=l15=q, row=mf*16+lg*4+r = key)
    f32x4 s2[4] = {};
#pragma unroll
    for (int kd = 0; kd < 2; ++kd) {
      bf16x8 kf[4];
#pragma unroll
      for (int mf = 0; mf < 4; ++mf) {
        int row = mf * 16 + l15;
        int sl = (kd * 4 + lg) ^ (row & 7);
        kf[mf] = *(const bf16x8*)(Kc + row * 128 + sl * 16);
      }
      __builtin_amdgcn_s_setprio(1);
#pragma unroll
      for (int mf = 0; mf < 4; ++mf)
        s2[mf] = __builtin_amdgcn_mfma_f32_16x16x32_bf16(
            kf[mf], qf[kd], s2[mf], 0, 0, 0);
      __builtin_amdgcn_s_setprio(0);
    }

    // P = exp2(s*cc + mb), packed to bf16 pairs — stays in registers
    uint32_t pkw[4][2];
#pragma unroll
    for (int mf = 0; mf < 4; ++mf) {
      float p0 = exp2f(fmaf(s2[mf][0], cc, bf2f(mraw[mf][0])));
      float p1 = exp2f(fmaf(s2[mf][1], cc, bf2f(mraw[mf][1])));
      float p2 = exp2f(fmaf(s2[mf][2], cc, bf2f(mraw[mf][2])));
      float p3 = exp2f(fmaf(s2[mf][3], cc, bf2f(mraw[mf][3])));
      lrow += (p0 + p1) + (p2 + p3);
      asm("v_cvt_pk_bf16_f32 %0, %1, %2" : "=v"(pkw[mf][0]) : "v"(p0), "v"(p1));
      asm("v_cvt_pk_bf16_f32 %0, %1, %2" : "=v"(pkw[mf][1]) : "v"(p2), "v"(p3));
    }

    // O += P V : A-frag = {w0,w1 of mf=2kk, w0,w1 of mf=2kk+1} (in-lane!)
#pragma unroll
    for (int kk = 0; kk < 2; ++kk) {
      bf16x8 pf, vf[4];
      {
        union { uint32_t u[4]; bf16x8 v; } pu;
        pu.u[0] = pkw[2 * kk][0];
        pu.u[1] = pkw[2 * kk][1];
        pu.u[2] = pkw[2 * kk + 1][0];
        pu.u[3] = pkw[2 * kk + 1][1];
        pf = pu.v;
      }
#pragma unroll
      for (int df = 0; df < 4; ++df) {
        int row = df * 16 + l15;
        int sl = (kk * 4 + lg) ^ (row & 7);
        vf[df] = *(const bf16x8*)(Vc + row * 128 + sl * 16);
      }
      __builtin_amdgcn_s_setprio(1);
#pragma unroll
      for (int df = 0; df < 4; ++df)
        o[df] = __builtin_amdgcn_mfma_f32_16x16x32_bf16(
            pf, vf[df], o[df], 0, 0, 0);
      __builtin_amdgcn_s_setprio(0);
    }
    __syncthreads();  // implicit vmcnt(0): prefetch landed; all waves done cur
  }
#undef STAGE

  // l-reduction across lg groups, redistribute to epilogue rows
  float inv[4];
  {
    float t = lrow;
    t += __shfl_xor(t, 16);
    t += __shfl_xor(t, 32);
    float ti = (t > 0.f) ? 1.0f / t : 0.f;
#pragma unroll
    for (int r = 0; r < 4; ++r)
      inv[r] = __shfl(ti, (lane & 48) | (lg * 4 + r));
  }

  // epilogue: per-wave scratch aliasing the dead K buffer (post final barrier)
  char* wbase = (char*)&Ks[0][0] + w * 2304;
#pragma unroll
  for (int df = 0; df < 4; ++df)
#pragma unroll
    for (int r = 0; r < 4; ++r) {
      int prow = lg * 4 + r;
      *(u16*)(wbase + prow * 144 + (df * 16 + l15) * 2) =
          f2bf(o[df][r] * inv[r]);
    }
  asm volatile("s_waitcnt lgkmcnt(0)" ::: "memory");
  __builtin_amdgcn_sched_barrier(0);
  {
    int rowL = lane >> 2;            // 0..15
    int cpart = lane & 3;
    int grow = b * T_ + q0 + w * 16 + rowL;
#pragma unroll
    for (int j = 0; j < 2; ++j) {
      int chunk = cpart + 4 * j;     // 0..7 chunks of 8 u16
      u16x8 v = *(const u16x8*)(wbase + rowL * 144 + chunk * 16);
      *(u16x8*)(outb + (size_t)grow * E_ + h * D_ + chunk * 8) = v;
    }
  }
}

extern "C" void kernel_launch(void* const* d_in, const int* in_sizes, int n_in,
                              void* d_out, int out_size, void* d_ws, size_t ws_size,
                              hipStream_t stream) {
  const void* x    = d_in[0];
  // d_in[1] physics_state: UNUSED — per-(b,h) scalar bias cancels in softmax.
  const void* mask = d_in[2];
  const void* Wq = d_in[3];
  const void* bq = d_in[4];
  const void* Wk = d_in[5];
  const void* bk = d_in[6];
  const void* Wv = d_in[7];
  const void* bv = d_in[8];
  const void* Wo = d_in[9];
  const void* bo = d_in[10];
  char* ws = (char*)d_ws;

  // ---- workspace plan (~26.1 MB). d_out (16 MB f32) doubles as scratch:
  // Qb bf16 lower 8 MB, xc bf16 upper 8 MB; both dead before the final
  // f32 GEMM overwrites d_out. ----
  const size_t MB = 1024 * 1024;
  u16* Kb   = (u16*)(ws + 0 * MB);          // 8 MB (B,H,T,D)
  u16* Vtb  = (u16*)(ws + 8 * MB);          // 8 MB (B,H,D,T) key-permuted
  u16* Ab   = (u16*)(ws + 16 * MB);         // 8 MB attn out (B,T,E) bf16
  u16* WqT  = (u16*)(ws + 16 * MB);         // WqT|WkT|WvT overlay Ab (dead
  u16* WkT  = (u16*)(ws + 18 * MB);         //  before attn writes Ab)
  u16* WvT  = (u16*)(ws + 20 * MB);
  u16* WoT  = (u16*)(ws + 24 * MB);         // own 2 MB (read by gemm_out)
  u16* bqc  = (u16*)(ws + 26 * MB);         // 4 bias slots, 2048 elems apart
  u16* boc  = bqc + 3 * 2048;
  u16* mbg  = (u16*)(ws + 26 * MB + 32 * 1024);   // 8 KB (bf16)

  u16* Qb = (u16*)d_out;                     // lower 8 MB of d_out
  u16* xc = (u16*)((char*)d_out + 8 * MB);   // upper 8 MB of d_out
  float* out = (float*)d_out;

  dim3 blk(256);
  const int NX = B_ * T_ * E_;     // 4M elems

  convf_kernel<<<NX / 8 / 256, blk, 0, stream>>>(x, xc, NX);
  bias4_kernel<<<4, blk, 0, stream>>>(bq, bk, bv, bo, bqc);
  maskbias_kernel<<<16, blk, 0, stream>>>(mask, mbg);
  wtc4_kernel<<<dim3(16, 16, 4), blk, 0, stream>>>(Wq, Wk, Wv, Wo,
                                                   WqT, WkT, WvT, WoT);
  gemm_qkv_kernel<<<dim3(32, 24), blk, 0, stream>>>(xc, WqT, bqc, Qb, Kb, Vtb);
  attn_kernel<<<dim3(1024), blk, 0, stream>>>(Qb, Kb, Vtb, mbg, Ab);
  gemm_out_kernel<<<dim3(32, 8), blk, 0, stream>>>(Ab, WoT, boc, out);
}

// Round 13
// 129.202 us; speedup vs baseline: 1.0225x; 1.0225x over previous
//
#include <hip/hip_runtime.h>
#include <hip/hip_bf16.h>
#include <stdint.h>

// Problem constants
#define E_  1024
#define H_  16
#define D_  64
#define T_  2048
#define B_  2

typedef unsigned short u16;
typedef unsigned char u8;
typedef __attribute__((ext_vector_type(8))) __bf16 bf16x8;
typedef __attribute__((ext_vector_type(4))) float f32x4;
typedef __attribute__((ext_vector_type(8))) u16 u16x8;
typedef __attribute__((ext_vector_type(4))) u16 u16x4;

__device__ __forceinline__ float bf2f(u16 u) {
  union { uint32_t u32; float f; } x; x.u32 = ((uint32_t)u) << 16; return x.f;
}
__device__ __forceinline__ u16 f2bf(float v) {
  union { float f; uint32_t u; } x; x.f = v;
  uint32_t r = x.u + 0x7fffu + ((x.u >> 16) & 1u);  // round-to-nearest-even
  return (u16)(r >> 16);
}
__device__ __forceinline__ void async16(const void* g, void* l) {
  __builtin_amdgcn_global_load_lds(
      (const __attribute__((address_space(1))) void*)g,
      (__attribute__((address_space(3))) void*)l, 16, 0, 0);
}
// key permutation within a 64-key tile: LDS/MFMA k-order j for actual key k.
// j = {K5, K3, K2, K4, K1, K0}  (so producer P registers == PV A-fragment)
__device__ __forceinline__ int jperm(int k) {
  return (k & 35) | ((k & 12) << 1) | ((k & 16) >> 2);
}

// Per-kernel dtype self-detection (wave-uniform): sample even u16 halves of
// the tensor's first 256B. bf16 -> exponents ~[118,130]; f32 low-halves are
// mantissa bits -> ~37-50% extreme. All-zero -> bf16 path (harmless).
__device__ __forceinline__ int detect_f32(const void* src) {
  u16 u = ((const u16*)src)[2 * (threadIdx.x & 63)];
  int e = (u >> 7) & 0xFF;
  int ex = (e != 0 && (e <= 0x40 || e >= 0xC0)) ? 1 : 0;
  return __popcll(__ballot(ex)) > 16;
}

// canonicalize x to bf16
__global__ __launch_bounds__(256) void convf_kernel(const void* __restrict__ src,
                                                    u16* __restrict__ dst, int n) {
  const int f32in = detect_f32(src);
  int i = (blockIdx.x * 256 + threadIdx.x) * 8;
  if (i >= n) return;
  if (f32in) {
    const float* s = (const float*)src;
    u16x8 o;
#pragma unroll
    for (int j = 0; j < 8; ++j) o[j] = f2bf(s[i + j]);
    *(u16x8*)(dst + i) = o;
  } else {
    *(u16x8*)(dst + i) = *(const u16x8*)((const u16*)src + i);
  }
}

// all four biases in one dispatch; dst slots spaced 2048 elems apart
__global__ __launch_bounds__(256) void bias4_kernel(
    const void* __restrict__ b0, const void* __restrict__ b1,
    const void* __restrict__ b2, const void* __restrict__ b3,
    u16* __restrict__ dst) {
  const void* src = (blockIdx.x == 0) ? b0 : (blockIdx.x == 1) ? b1
                    : (blockIdx.x == 2) ? b2 : b3;
  const int f32in = detect_f32(src);
  u16* d = dst + blockIdx.x * 2048;
  int t = threadIdx.x;
#pragma unroll
  for (int j = 0; j < 4; ++j) {
    int i = t + j * 256;
    d[i] = f32in ? f2bf(((const float*)src)[i]) : ((const u16*)src)[i];
  }
}

// mask -> log2-domain additive constant: keep -> -SH, drop -> -30000
__global__ __launch_bounds__(256) void maskbias_kernel(const void* __restrict__ mp,
                                                       float* __restrict__ mbg) {
  unsigned w0 = ((const unsigned*)mp)[threadIdx.x & 63];
  int isInt = (__ballot(w0 > 1u) == 0ull);  // int32 bools are 0/1 only
  int i = blockIdx.x * 256 + threadIdx.x;   // 4096 total
  int keep = isInt ? (((const int*)mp)[i] != 0) : (((const u8*)mp)[i] != 0);
  mbg[i] = keep ? -5.77078016f : -30000.f;  // -4*log2(e) | masked
}

// fused weight convert + transpose, all 4 weights in one dispatch (z selects)
__global__ __launch_bounds__(256) void wtc4_kernel(
    const void* __restrict__ W0, const void* __restrict__ W1,
    const void* __restrict__ W2, const void* __restrict__ W3,
    u16* __restrict__ T0, u16* __restrict__ T1,
    u16* __restrict__ T2, u16* __restrict__ T3) {
  __shared__ __align__(16) u16 tile[64][65];
  const int z = blockIdx.z;
  const void* Wv = (z == 0) ? W0 : (z == 1) ? W1 : (z == 2) ? W2 : W3;
  u16* WT = (z == 0) ? T0 : (z == 1) ? T1 : (z == 2) ? T2 : T3;
  const int f32in = detect_f32(Wv);
  const int bx = blockIdx.x * 64, by = blockIdx.y * 64;
  const int t = threadIdx.x;
#pragma unroll
  for (int p = 0; p < 2; ++p) {
    int row = p * 32 + (t >> 3);
    int ch = t & 7;
    if (f32in) {
      const float* s = (const float*)Wv + (size_t)(by + row) * E_ + bx + ch * 8;
#pragma unroll
      for (int j = 0; j < 8; ++j) tile[row][ch * 8 + j] = f2bf(s[j]);
    } else {
      u16x8 v = *(const u16x8*)((const u16*)Wv + (size_t)(by + row) * E_ + bx + ch * 8);
#pragma unroll
      for (int j = 0; j < 8; ++j) tile[row][ch * 8 + j] = v[j];
    }
  }
  __syncthreads();
#pragma unroll
  for (int p = 0; p < 2; ++p) {
    int orow = p * 32 + (t >> 3);
    int ch = t & 7;
    u16x8 v;
#pragma unroll
    for (int j = 0; j < 8; ++j) v[j] = tile[ch * 8 + j][orow];
    *(u16x8*)(WT + (size_t)(bx + orow) * E_ + by + ch * 8) = v;
  }
}

// ---------------- fused QKV GEMM -------------------------------------------
// V^T is stored with jperm-permuted t-order within each 64-key block so the
// attention PV B-operand matches the in-register P fragments.
// launch_bounds (256,3): target 3 waves/SIMD -> 3 blocks/CU (was 2).
__global__ __launch_bounds__(256, 3) void gemm_qkv_kernel(
    const u16* __restrict__ A, const u16* __restrict__ BTm,
    const u16* __restrict__ biases, u16* __restrict__ Qb,
    u16* __restrict__ Kb, u16* __restrict__ Vtb) {
  __shared__ __align__(16) u16 As[128 * 64];
  __shared__ __align__(16) u16 Bs[128 * 64];
  const int tid = threadIdx.x, lane = tid & 63, wid = tid >> 6;
  const int wm = wid >> 1, wn = wid & 1;
  const int l15 = lane & 15, lg = lane >> 4;
  const int r0 = blockIdx.x * 128, c0 = blockIdx.y * 128;
  f32x4 acc[4][4] = {};

  for (int k0 = 0; k0 < E_; k0 += 64) {
    __syncthreads();
#pragma unroll
    for (int i = 0; i < 4; ++i) {
      int row = i * 32 + (tid >> 3);
      int g = (tid & 7) ^ (row & 7);
      async16(A + (size_t)(r0 + row) * E_ + k0 + g * 8,
              (char*)As + i * 4096 + tid * 16);
      async16(BTm + (size_t)(c0 + row) * E_ + k0 + g * 8,
              (char*)Bs + i * 4096 + tid * 16);
    }
    __syncthreads();
#pragma unroll
    for (int kk = 0; kk < 2; ++kk) {
      bf16x8 af[4], bfr[4];
#pragma unroll
      for (int mt = 0; mt < 4; ++mt) {
        int rowa = wm * 64 + mt * 16 + l15;
        int sa = (kk * 4 + lg) ^ (rowa & 7);
        af[mt] = *(const bf16x8*)((const char*)As + rowa * 128 + sa * 16);
        int rowb = wn * 64 + mt * 16 + l15;
        int sb = (kk * 4 + lg) ^ (rowb & 7);
        bfr[mt] = *(const bf16x8*)((const char*)Bs + rowb * 128 + sb * 16);
      }
#pragma unroll
      for (int mt = 0; mt < 4; ++mt)
#pragma unroll
        for (int nt = 0; nt < 4; ++nt)
          acc[mt][nt] = __builtin_amdgcn_mfma_f32_16x16x32_bf16(
              af[mt], bfr[nt], acc[mt][nt], 0, 0, 0);
    }
  }

  const int sel = c0 >> 10;           // 0=Q, 1=K, 2=V
  u16* outp = (sel == 0) ? Qb : Kb;
#pragma unroll
  for (int mt = 0; mt < 4; ++mt) {
#pragma unroll
    for (int nt = 0; nt < 4; ++nt) {
      int colG = c0 + wn * 64 + nt * 16 + l15;
      int colL = colG & 1023;
      float bv = bf2f(biases[sel * 2048 + colL]);
      int rbase = r0 + wm * 64 + mt * 16 + lg * 4;
      int hh = colL >> 6, dd = colL & 63;
      if (sel == 2) {  // V^T (B,H,D,T) with jperm'd t within 64-blocks
        int bb = rbase >> 11, t0 = rbase & (T_ - 1);
        int tp = (t0 & ~63) | jperm(t0 & 63);   // low 2 bits preserved
        u16x4 pk;
#pragma unroll
        for (int r = 0; r < 4; ++r) pk[r] = f2bf(acc[mt][nt][r] + bv);
        *(u16x4*)(Vtb + (size_t)((bb * H_ + hh) * D_ + dd) * T_ + tp) = pk;
      } else {         // Q/K (B,H,T,D)
#pragma unroll
        for (int r = 0; r < 4; ++r) {
          int row = rbase + r;
          int bb = row >> 11, t = row & (T_ - 1);
          outp[(size_t)((bb * H_ + hh) * T_ + t) * D_ + dd] =
              f2bf(acc[mt][nt][r] + bv);
        }
      }
    }
  }
}

// ---------------- final GEMM: f32 output -----------------------------------
__global__ __launch_bounds__(256, 3) void gemm_out_kernel(
    const u16* __restrict__ A, const u16* __restrict__ BTm,
    const u16* __restrict__ bias, float* __restrict__ out) {
  __shared__ __align__(16) u16 As[128 * 64];
  __shared__ __align__(16) u16 Bs[128 * 64];
  const int tid = threadIdx.x, lane = tid & 63, wid = tid >> 6;
  const int wm = wid >> 1, wn = wid & 1;
  const int l15 = lane & 15, lg = lane >> 4;
  const int r0 = blockIdx.x * 128, c0 = blockIdx.y * 128;
  f32x4 acc[4][4] = {};

  for (int k0 = 0; k0 < E_; k0 += 64) {
    __syncthreads();
#pragma unroll
    for (int i = 0; i < 4; ++i) {
      int row = i * 32 + (tid >> 3);
      int g = (tid & 7) ^ (row & 7);
      async16(A + (size_t)(r0 + row) * E_ + k0 + g * 8,
              (char*)As + i * 4096 + tid * 16);
      async16(BTm + (size_t)(c0 + row) * E_ + k0 + g * 8,
              (char*)Bs + i * 4096 + tid * 16);
    }
    __syncthreads();
#pragma unroll
    for (int kk = 0; kk < 2; ++kk) {
      bf16x8 af[4], bfr[4];
#pragma unroll
      for (int mt = 0; mt < 4; ++mt) {
        int rowa = wm * 64 + mt * 16 + l15;
        int sa = (kk * 4 + lg) ^ (rowa & 7);
        af[mt] = *(const bf16x8*)((const char*)As + rowa * 128 + sa * 16);
        int rowb = wn * 64 + mt * 16 + l15;
        int sb = (kk * 4 + lg) ^ (rowb & 7);
        bfr[mt] = *(const bf16x8*)((const char*)Bs + rowb * 128 + sb * 16);
      }
#pragma unroll
      for (int mt = 0; mt < 4; ++mt)
#pragma unroll
        for (int nt = 0; nt < 4; ++nt)
          acc[mt][nt] = __builtin_amdgcn_mfma_f32_16x16x32_bf16(
              af[mt], bfr[nt], acc[mt][nt], 0, 0, 0);
    }
  }

#pragma unroll
  for (int mt = 0; mt < 4; ++mt)
#pragma unroll
    for (int nt = 0; nt < 4; ++nt) {
      int col = c0 + wn * 64 + nt * 16 + l15;
      float bv = bf2f(bias[col]);
      int rbase = r0 + wm * 64 + mt * 16 + lg * 4;
#pragma unroll
      for (int r = 0; r < 4; ++r)
        out[(size_t)(rbase + r) * E_ + col] = acc[mt][nt][r] + bv;
    }
}

// ---------------- MFMA flash attention (counted-vmcnt 2-deep pipeline) ------
// r11 structure (best measured): q-tile 128, 4 waves x 32 q-rows, P fully in
// registers (swapped QK^T + jperm'd V), 3 LDS K/V buffers, 2-deep prefetch,
// raw s_barrier + counted vmcnt(4). Mask bias in LDS f32.
__global__ __launch_bounds__(256, 2) void attn_kernel(
    const u16* __restrict__ Q, const u16* __restrict__ K,
    const u16* __restrict__ VT, const float* __restrict__ mbg,
    u16* __restrict__ outb) {
  __shared__ __align__(16) u16 Ks[3][64 * 64];      // [buf][key][d] swizzled
  __shared__ __align__(16) u16 Vs[3][64 * 64];      // [buf][d][key-perm] swz
  __shared__ __align__(16) float mb[T_];            // log2-domain mask bias
  __shared__ __align__(16) u16 oscr[4][2304];       // per-wave epilogue scratch
  // XCD-local decode: all 16 q-blocks of a head land on one XCD (L2 reuse)
  const int wg = blockIdx.x;
  const int xcd = wg & 7, slot = wg >> 3;
  const int bh = xcd + 8 * (slot >> 4);
  const int q0 = (slot & 15) * 128;
  const int b = bh >> 4, h = bh & 15;
  const int tid = threadIdx.x, lane = tid & 63, w = tid >> 6;
  const int l15 = lane & 15, lg = lane >> 4;

  const u16* qb = Q + (size_t)bh * T_ * D_;
  const u16* kb = K + (size_t)bh * T_ * D_;
  const u16* vb = VT + (size_t)bh * D_ * T_;

  // mask bias -> LDS (once)
  {
    const f32x4* s = (const f32x4*)(mbg + b * T_);
    f32x4* d = (f32x4*)mb;
#pragma unroll
    for (int j = 0; j < 2; ++j) d[tid + j * 256] = s[tid + j * 256];
  }

  bf16x8 qf[2][2];  // Q hoisted: B-frag col=l15(q), k=kd*32+lg*8
#pragma unroll
  for (int mt = 0; mt < 2; ++mt)
#pragma unroll
    for (int kd = 0; kd < 2; ++kd) {
      int row = q0 + w * 32 + mt * 16 + l15;
      qf[mt][kd] = *(const bf16x8*)(qb + (size_t)row * D_ + kd * 32 + lg * 8);
    }

#define STAGE(kt_, bi_)                                                  \
  do {                                                                   \
    _Pragma("unroll")                                                    \
    for (int c = 0; c < 2; ++c) {                                        \
      int row_ = c * 32 + (tid >> 3);                                    \
      int g_ = (tid & 7) ^ (row_ & 7);                                   \
      async16(kb + (size_t)((kt_) * 64 + row_) * D_ + g_ * 8,            \
              (char*)&Ks[bi_][0] + c * 4096 + tid * 16);                 \
      async16(vb + (size_t)row_ * T_ + (kt_) * 64 + g_ * 8,              \
              (char*)&Vs[bi_][0] + c * 4096 + tid * 16);                 \
    }                                                                    \
  } while (0)

  STAGE(0, 0);
  STAGE(1, 1);
  asm volatile("s_waitcnt lgkmcnt(0)" ::: "memory");  // mb writes drained

  f32x4 o[2][4] = {};
  float lrow[2] = {0.f, 0.f};
  const float cc = 0.125f * 1.44269504f;  // scale * log2(e)

  int rd = 0, wr = 2;  // read buf = kt%3, write buf = (kt+2)%3
  for (int kt = 0; kt < 32; ++kt) {
    if (kt < 31)
      asm volatile("s_waitcnt vmcnt(4)" ::: "memory");  // STAGE(kt) landed
    else
      asm volatile("s_waitcnt vmcnt(0)" ::: "memory");
    __builtin_amdgcn_sched_barrier(0);
    __builtin_amdgcn_s_barrier();      // all waves: tile kt ready, kt-1 done
    __builtin_amdgcn_sched_barrier(0);
    if (kt < 30) STAGE(kt + 2, wr);    // overwrite buf last read at kt-1
    const char* Kc = (const char*)&Ks[rd][0];
    const char* Vc = (const char*)&Vs[rd][0];

    // mask bias for this tile (LDS broadcast; hidden under QK^T)
    f32x4 mbv4[4];
#pragma unroll
    for (int mf = 0; mf < 4; ++mf)
      mbv4[mf] = *(const f32x4*)&mb[kt * 64 + mf * 16 + lg * 4];

    // S^T = K Q^T  (C: col=l15=q, row=mf*16+lg*4+r = key)
    f32x4 s2[2][4] = {};
#pragma unroll
    for (int kd = 0; kd < 2; ++kd) {
      bf16x8 kf[4];
#pragma unroll
      for (int mf = 0; mf < 4; ++mf) {
        int row = mf * 16 + l15;
        int sl = (kd * 4 + lg) ^ (row & 7);
        kf[mf] = *(const bf16x8*)(Kc + row * 128 + sl * 16);
      }
      __builtin_amdgcn_s_setprio(1);
#pragma unroll
      for (int mt = 0; mt < 2; ++mt)
#pragma unroll
        for (int mf = 0; mf < 4; ++mf)
          s2[mt][mf] = __builtin_amdgcn_mfma_f32_16x16x32_bf16(
              kf[mf], qf[mt][kd], s2[mt][mf], 0, 0, 0);
      __builtin_amdgcn_s_setprio(0);
    }

    // P = exp2(s*cc + mb), packed to bf16 pairs — stays in registers
    uint32_t pkw[2][4][2];
#pragma unroll
    for (int mt = 0; mt < 2; ++mt) {
#pragma unroll
      for (int mf = 0; mf < 4; ++mf) {
        float p0 = exp2f(fmaf(s2[mt][mf][0], cc, mbv4[mf][0]));
        float p1 = exp2f(fmaf(s2[mt][mf][1], cc, mbv4[mf][1]));
        float p2 = exp2f(fmaf(s2[mt][mf][2], cc, mbv4[mf][2]));
        float p3 = exp2f(fmaf(s2[mt][mf][3], cc, mbv4[mf][3]));
        lrow[mt] += (p0 + p1) + (p2 + p3);
        asm("v_cvt_pk_bf16_f32 %0, %1, %2" : "=v"(pkw[mt][mf][0]) : "v"(p0), "v"(p1));
        asm("v_cvt_pk_bf16_f32 %0, %1, %2" : "=v"(pkw[mt][mf][1]) : "v"(p2), "v"(p3));
      }
    }

    // O += P V : A-frag = {w0,w1 of mf=2kk, w0,w1 of mf=2kk+1} (in-lane!)
#pragma unroll
    for (int kk = 0; kk < 2; ++kk) {
      bf16x8 pf[2], vf[4];
#pragma unroll
      for (int mt = 0; mt < 2; ++mt) {
        union { uint32_t u[4]; bf16x8 v; } pu;
        pu.u[0] = pkw[mt][2 * kk][0];
        pu.u[1] = pkw[mt][2 * kk][1];
        pu.u[2] = pkw[mt][2 * kk + 1][0];
        pu.u[3] = pkw[mt][2 * kk + 1][1];
        pf[mt] = pu.v;
      }
#pragma unroll
      for (int df = 0; df < 4; ++df) {
        int row = df * 16 + l15;
        int sl = (kk * 4 + lg) ^ (row & 7);
        vf[df] = *(const bf16x8*)(Vc + row * 128 + sl * 16);
      }
      __builtin_amdgcn_s_setprio(1);
#pragma unroll
      for (int mt = 0; mt < 2; ++mt)
#pragma unroll
        for (int df = 0; df < 4; ++df)
          o[mt][df] = __builtin_amdgcn_mfma_f32_16x16x32_bf16(
              pf[mt], vf[df], o[mt][df], 0, 0, 0);
      __builtin_amdgcn_s_setprio(0);
    }
    rd = (rd == 2) ? 0 : rd + 1;
    wr = (wr == 2) ? 0 : wr + 1;
  }
#undef STAGE

  // l-reduction across lg groups, redistribute to epilogue rows
  float inv[2][4];
#pragma unroll
  for (int mt = 0; mt < 2; ++mt) {
    float t = lrow[mt];
    t += __shfl_xor(t, 16);
    t += __shfl_xor(t, 32);
    float ti = (t > 0.f) ? 1.0f / t : 0.f;
#pragma unroll
    for (int r = 0; r < 4; ++r)
      inv[mt][r] = __shfl(ti, (lane & 48) | (lg * 4 + r));
  }

  // epilogue: per-wave private scratch (no aliasing with live tiles)
  char* wbase = (char*)&oscr[w][0];
#pragma unroll
  for (int mt = 0; mt < 2; ++mt)
#pragma unroll
    for (int df = 0; df < 4; ++df)
#pragma unroll
      for (int r = 0; r < 4; ++r) {
        int prow = mt * 16 + lg * 4 + r;
        *(u16*)(wbase + prow * 144 + (df * 16 + l15) * 2) =
            f2bf(o[mt][df][r] * inv[mt][r]);
      }
  asm volatile("s_waitcnt lgkmcnt(0)" ::: "memory");
  __builtin_amdgcn_sched_barrier(0);
  {
    int rowL = lane >> 1;
    int c8 = lane & 1;
    int grow = b * T_ + q0 + w * 32 + rowL;
#pragma unroll
    for (int j = 0; j < 4; ++j) {
      int chunk = c8 + 2 * j;
      u16x8 v = *(const u16x8*)(wbase + rowL * 144 + chunk * 16);
      *(u16x8*)(outb + (size_t)grow * E_ + h * D_ + chunk * 8) = v;
    }
  }
}

extern "C" void kernel_launch(void* const* d_in, const int* in_sizes, int n_in,
                              void* d_out, int out_size, void* d_ws, size_t ws_size,
                              hipStream_t stream) {
  const void* x    = d_in[0];
  // d_in[1] physics_state: UNUSED — per-(b,h) scalar bias cancels in softmax.
  const void* mask = d_in[2];
  const void* Wq = d_in[3];
  const void* bq = d_in[4];
  const void* Wk = d_in[5];
  const void* bk = d_in[6];
  const void* Wv = d_in[7];
  const void* bv = d_in[8];
  const void* Wo = d_in[9];
  const void* bo = d_in[10];
  char* ws = (char*)d_ws;

  // ---- workspace plan (~26.1 MB). d_out (16 MB f32) doubles as scratch:
  // Qb bf16 lower 8 MB, xc bf16 upper 8 MB; both dead before the final
  // f32 GEMM overwrites d_out. ----
  const size_t MB = 1024 * 1024;
  u16* Kb   = (u16*)(ws + 0 * MB);          // 8 MB (B,H,T,D)
  u16* Vtb  = (u16*)(ws + 8 * MB);          // 8 MB (B,H,D,T) key-permuted
  u16* Ab   = (u16*)(ws + 16 * MB);         // 8 MB attn out (B,T,E) bf16
  u16* WqT  = (u16*)(ws + 16 * MB);         // WqT|WkT|WvT overlay Ab (dead
  u16* WkT  = (u16*)(ws + 18 * MB);         //  before attn writes Ab)
  u16* WvT  = (u16*)(ws + 20 * MB);
  u16* WoT  = (u16*)(ws + 24 * MB);         // own 2 MB (read by gemm_out)
  u16* bqc  = (u16*)(ws + 26 * MB);         // 4 bias slots, 2048 elems apart
  u16* boc  = bqc + 3 * 2048;
  float* mbg = (float*)(ws + 26 * MB + 32 * 1024);   // 16 KB

  u16* Qb = (u16*)d_out;                     // lower 8 MB of d_out
  u16* xc = (u16*)((char*)d_out + 8 * MB);   // upper 8 MB of d_out
  float* out = (float*)d_out;

  dim3 blk(256);
  const int NX = B_ * T_ * E_;     // 4M elems

  convf_kernel<<<NX / 8 / 256, blk, 0, stream>>>(x, xc, NX);
  bias4_kernel<<<4, blk, 0, stream>>>(bq, bk, bv, bo, bqc);
  maskbias_kernel<<<16, blk, 0, stream>>>(mask, mbg);
  wtc4_kernel<<<dim3(16, 16, 4), blk, 0, stream>>>(Wq, Wk, Wv, Wo,
                                                   WqT, WkT, WvT, WoT);
  gemm_qkv_kernel<<<dim3(32, 24), blk, 0, stream>>>(xc, WqT, bqc, Qb, Kb, Vtb);
  attn_kernel<<<dim3(512), blk, 0, stream>>>(Qb, Kb, Vtb, mbg, Ab);
  gemm_out_kernel<<<dim3(32, 8), blk, 0, stream>>>(Ab, WoT, boc, out);
}